// Round 9
// baseline (344.231 us; speedup 1.0000x reference)
//
#include <hip/hip_runtime.h>

#define HW 16384
#define CC 192
#define C3 576
#define NB 8
#define NH 8

typedef __attribute__((ext_vector_type(8))) short bfrag;
typedef __attribute__((ext_vector_type(4))) float f32x4;
typedef __attribute__((ext_vector_type(4))) unsigned short us4;

#define MFMA16(a, b, c) __builtin_amdgcn_mfma_f32_16x16x32_bf16(a, b, c, 0, 0, 0)

typedef __attribute__((address_space(3))) unsigned int lds_u32;
typedef __attribute__((address_space(1))) unsigned int glb_u32;
__device__ __forceinline__ void gl_lds16(const void* g, void* l) {
  __builtin_amdgcn_global_load_lds((const glb_u32*)g, (lds_u32*)l, 16, 0, 0);
}

__device__ __forceinline__ unsigned short f2bf(float f) {
  unsigned int u = __float_as_uint(f);
  u += 0x7fffu + ((u >> 16) & 1u);
  return (unsigned short)(u >> 16);
}
__device__ __forceinline__ float bf2f(unsigned short s) {
  return __uint_as_float(((unsigned int)s) << 16);
}
__device__ __forceinline__ float bf2f_s(short s) {
  return __uint_as_float(((unsigned int)(unsigned short)s) << 16);
}

// ---------------- workspace layout (bytes) ----------------
#define OFF_XT   0ull
#define SZ_XT    ((size_t)NB * HW * CC * 2)      // x transposed bf16 [b][hw][192]; later reused as VT
#define OFF_WQ   (OFF_XT + SZ_XT)
#define SZ_WQ    ((size_t)C3 * CC * 2)           // W packed into MFMA frag order
#define OFF_QKV  (OFF_WQ + SZ_WQ)
#define SZ_QKV   ((size_t)NB * C3 * HW * 2)      // qkv (pre-dw) bf16 [b][576][hw]
#define OFF_S    (OFF_QKV + SZ_QKV)
#define SZ_S     ((size_t)NB * NH * 32 * 32 * 4) // gram fp32 [b][h][32][32]
#define OFF_SSQ  (OFF_S + SZ_S)
#define SZ_SSQ   ((size_t)NB * 384 * 4)          // sumsq fp32 [b][q:192 | k:192]
#define OFF_M    (OFF_SSQ + SZ_SSQ)
#define SZ_M     ((size_t)NB * CC * CC * 2)      // fused proj*attn, packed frag order

// ---------------- prep: x -> bf16 transposed [b][hw][c] ----------------
__global__ __launch_bounds__(256) void k_xt(const float* __restrict__ x,
                                            unsigned short* __restrict__ xt) {
  __shared__ unsigned short tile[64 * 72];
  const int pb = blockIdx.x * 64;
  const int cb = blockIdx.y * 64;
  const int b  = blockIdx.z;
  const int t  = threadIdx.x;
  {
    const int cl = t >> 2, pl = (t & 3) * 16;
    const float* src = x + ((size_t)b * CC + cb + cl) * HW + pb + pl;
    bfrag v0, v1;
#pragma unroll
    for (int q4 = 0; q4 < 2; ++q4) {
      float4 f = *reinterpret_cast<const float4*>(src + q4 * 4);
      v0[q4 * 4 + 0] = (short)f2bf(f.x); v0[q4 * 4 + 1] = (short)f2bf(f.y);
      v0[q4 * 4 + 2] = (short)f2bf(f.z); v0[q4 * 4 + 3] = (short)f2bf(f.w);
    }
#pragma unroll
    for (int q4 = 0; q4 < 2; ++q4) {
      float4 f = *reinterpret_cast<const float4*>(src + 8 + q4 * 4);
      v1[q4 * 4 + 0] = (short)f2bf(f.x); v1[q4 * 4 + 1] = (short)f2bf(f.y);
      v1[q4 * 4 + 2] = (short)f2bf(f.z); v1[q4 * 4 + 3] = (short)f2bf(f.w);
    }
    *reinterpret_cast<bfrag*>(&tile[cl * 72 + pl]) = v0;
    *reinterpret_cast<bfrag*>(&tile[cl * 72 + pl + 8]) = v1;
  }
  __syncthreads();
  {
    const int pl = t >> 2, cl = (t & 3) * 16;
    bfrag o0, o1;
#pragma unroll
    for (int e = 0; e < 8; ++e) o0[e] = (short)tile[(cl + e) * 72 + pl];
#pragma unroll
    for (int e = 0; e < 8; ++e) o1[e] = (short)tile[(cl + 8 + e) * 72 + pl];
    unsigned short* dst = xt + ((size_t)b * HW + pb + pl) * CC + cb + cl;
    *reinterpret_cast<bfrag*>(dst) = o0;
    *reinterpret_cast<bfrag*>(dst + 8) = o1;
  }
}

// ---------------- prep: pack W into MFMA fragment order ----------------
__global__ __launch_bounds__(256) void k_wpack(const float* __restrict__ w,
                                               unsigned short* __restrict__ wp) {
  const int g = blockIdx.x * 256 + threadIdx.x;
  if (g >= 216 * 64) return;
  const int frag = g >> 6, lane = g & 63;
  const int mb = frag / 24, r = frag % 24, s = r >> 2, i = r & 3;
  const int row = mb * 64 + i * 16 + (lane & 15);
  const int col = s * 32 + (lane >> 4) * 8;
  const float* src = w + (size_t)row * CC + col;
  float4 f0 = *reinterpret_cast<const float4*>(src);
  float4 f1 = *reinterpret_cast<const float4*>(src + 4);
  us4 o0, o1;
  o0[0] = f2bf(f0.x); o0[1] = f2bf(f0.y); o0[2] = f2bf(f0.z); o0[3] = f2bf(f0.w);
  o1[0] = f2bf(f1.x); o1[1] = f2bf(f1.y); o1[2] = f2bf(f1.z); o1[3] = f2bf(f1.w);
  *reinterpret_cast<us4*>(wp + (size_t)g * 8) = o0;
  *reinterpret_cast<us4*>(wp + (size_t)g * 8 + 4) = o1;
}

// ---------------- qkv GEMM (R8-proven) ----------------
__global__ __launch_bounds__(256, 3) void k_gemm_qkv(const unsigned short* __restrict__ Wp,
                                                     const unsigned short* __restrict__ Xt,
                                                     unsigned short* __restrict__ Y) {
  __shared__ __attribute__((aligned(16))) char sB[49152];
  const int nb = blockIdx.x;
  const int b  = blockIdx.y;
  const int tid = threadIdx.x;
  const int wave = tid >> 6, lane = tid & 63;
  const int lrow = lane & 15, lk = (lane >> 4) * 8, lr4 = (lane >> 4) * 4;

  const char* Bc = (const char*)(Xt + ((size_t)b * HW + (size_t)nb * 128) * CC);
#pragma unroll
  for (int t = 0; t < 12; ++t) {
    const int L = wave * 12288 + t * 1024 + lane * 16;
    const int row = L / 384;
    const int rem = L - row * 384;
    gl_lds16(Bc + row * 384 + (rem ^ ((row & 7) << 4)), sB + wave * 12288 + t * 1024);
  }
  asm volatile("s_waitcnt vmcnt(0)" ::: "memory");
  __syncthreads();

  const int swz = (lrow & 7) << 4;
  const int base0 = (wave * 32 + lrow) * 384;
  const f32x4 z4 = {0.f, 0.f, 0.f, 0.f};

#pragma unroll 1
  for (int mb = 0; mb < 9; ++mb) {
    const unsigned short* Wb = Wp + (size_t)mb * 24 * 512;
    bfrag af[6][4];
#pragma unroll
    for (int s = 0; s < 6; ++s)
#pragma unroll
      for (int i = 0; i < 4; ++i)
        af[s][i] = *reinterpret_cast<const bfrag*>(Wb + ((s * 4 + i) * 64 + lane) * 8);

    f32x4 acc[4][2];
#pragma unroll
    for (int i = 0; i < 4; ++i) { acc[i][0] = z4; acc[i][1] = z4; }
#pragma unroll
    for (int s = 0; s < 6; ++s) {
      const int kbs = ((s * 32 + lk) * 2) ^ swz;
      bfrag b0 = *reinterpret_cast<const bfrag*>(sB + base0 + kbs);
      bfrag b1 = *reinterpret_cast<const bfrag*>(sB + base0 + 16 * 384 + kbs);
#pragma unroll
      for (int i = 0; i < 4; ++i) {
        acc[i][0] = MFMA16(b0, af[s][i], acc[i][0]);  // D[px][ch]
        acc[i][1] = MFMA16(b1, af[s][i], acc[i][1]);
      }
    }
    unsigned short* Yb = Y + ((size_t)b * C3 + mb * 64) * HW + nb * 128 + wave * 32;
#pragma unroll
    for (int i = 0; i < 4; ++i) {
      unsigned short* rp = Yb + (size_t)(i * 16 + lrow) * HW;
#pragma unroll
      for (int j = 0; j < 2; ++j) {
        uint2 pk;
        pk.x = (unsigned int)f2bf(acc[i][j][0]) | ((unsigned int)f2bf(acc[i][j][1]) << 16);
        pk.y = (unsigned int)f2bf(acc[i][j][2]) | ((unsigned int)f2bf(acc[i][j][3]) << 16);
        *reinterpret_cast<uint2*>(rp + j * 16 + lr4) = pk;
      }
    }
  }
}

// ---------------- fused dwconv(q,k) + gram + ssq ----------------
// Block: (strip of 2048px, head, b). dwconv results -> LDS bf16; gram MFMA from
// LDS; ssq from f32 accs. Writes only S (atomic) + ssq (atomic).
__global__ __launch_bounds__(256, 2) void k_dwgram(const unsigned short* __restrict__ QKV,
                                                   const float* __restrict__ wd,
                                                   float* __restrict__ S,
                                                   float* __restrict__ ssq) {
  __shared__ short lds[56 * 520];  // rows 0..23 q, 24..47 k, 48..55 slack
  const int strip = blockIdx.x, h = blockIdx.y, b = blockIdx.z;
  const int tid = threadIdx.x, wave = tid >> 6, lane = tid & 63;
  const int lrow = lane & 15, lk8 = (lane >> 4) * 8, lr4 = (lane >> 4) * 4;
  const size_t qbase = ((size_t)b * C3 + h * 24) * HW;
  const size_t kbase = qbase + (size_t)192 * HW;

  const int p = lane * 8;       // px within 512-chunk
  const int x0 = p & 127;

  float sqp[6] = {0.f, 0.f, 0.f, 0.f, 0.f, 0.f};
  float skp[6] = {0.f, 0.f, 0.f, 0.f, 0.f, 0.f};
  f32x4 acc[2][2];
  const f32x4 z4 = {0.f, 0.f, 0.f, 0.f};
#pragma unroll
  for (int i = 0; i < 2; ++i) { acc[i][0] = z4; acc[i][1] = z4; }

  auto dwconv8 = [&](const unsigned short* ip, const float* w, int y, float* facc) {
#pragma unroll
    for (int e = 0; e < 8; ++e) facc[e] = 0.f;
#pragma unroll
    for (int dy = 0; dy < 3; ++dy) {
      int yy = y + dy - 1;
      if (yy < 0 || yy > 127) continue;
      const unsigned short* row = ip + yy * 128;
      bfrag v = *reinterpret_cast<const bfrag*>(row + x0);
      float c[8];
#pragma unroll
      for (int e = 0; e < 8; ++e) c[e] = bf2f_s(v[e]);
      float left  = (x0 > 0)   ? bf2f(row[x0 - 1]) : 0.f;
      float right = (x0 < 120) ? bf2f(row[x0 + 8]) : 0.f;
      float wl = w[dy * 3 + 0], wc = w[dy * 3 + 1], wr = w[dy * 3 + 2];
      facc[0] += wl * left + wc * c[0] + wr * c[1];
#pragma unroll
      for (int e = 1; e < 7; ++e) facc[e] += wl * c[e - 1] + wc * c[e] + wr * c[e + 1];
      facc[7] += wl * c[6] + wc * c[7] + wr * right;
    }
  };

#pragma unroll 1
  for (int chunk = 0; chunk < 4; ++chunk) {
    const int y = strip * 16 + chunk * 4 + (p >> 7);
#pragma unroll 1
    for (int j = 0; j < 6; ++j) {
      const int c = wave + 4 * j;
      float facc[8];
      // q channel
      dwconv8(QKV + qbase + (size_t)c * HW, wd + (h * 24 + c) * 9, y, facc);
      {
        float ss = 0.f;
        bfrag o;
#pragma unroll
        for (int e = 0; e < 8; ++e) { ss += facc[e] * facc[e]; o[e] = (short)f2bf(facc[e]); }
        sqp[j] += ss;
        *reinterpret_cast<bfrag*>(&lds[c * 520 + p]) = o;
      }
      // k channel
      dwconv8(QKV + kbase + (size_t)c * HW, wd + (192 + h * 24 + c) * 9, y, facc);
      {
        float ss = 0.f;
        bfrag o;
#pragma unroll
        for (int e = 0; e < 8; ++e) { ss += facc[e] * facc[e]; o[e] = (short)f2bf(facc[e]); }
        skp[j] += ss;
        *reinterpret_cast<bfrag*>(&lds[(24 + c) * 520 + p]) = o;
      }
    }
    __syncthreads();
#pragma unroll
    for (int ks = 0; ks < 4; ++ks) {
      const int pp = wave * 128 + ks * 32 + lk8;
      bfrag aq[2], bk[2];
#pragma unroll
      for (int i = 0; i < 2; ++i) {
        aq[i] = *reinterpret_cast<const bfrag*>(&lds[(i * 16 + lrow) * 520 + pp]);
        bk[i] = *reinterpret_cast<const bfrag*>(&lds[(24 + i * 16 + lrow) * 520 + pp]);
      }
#pragma unroll
      for (int i = 0; i < 2; ++i)
#pragma unroll
        for (int j2 = 0; j2 < 2; ++j2) acc[i][j2] = MFMA16(aq[i], bk[j2], acc[i][j2]);
    }
    __syncthreads();
  }

  float* Sb = S + (size_t)(b * 8 + h) * 1024;
#pragma unroll
  for (int i = 0; i < 2; ++i)
#pragma unroll
    for (int j2 = 0; j2 < 2; ++j2)
#pragma unroll
      for (int r = 0; r < 4; ++r)
        atomicAdd(&Sb[(i * 16 + lr4 + r) * 32 + j2 * 16 + lrow], acc[i][j2][r]);

#pragma unroll
  for (int j = 0; j < 6; ++j) {
    float v = sqp[j];
    float wv = skp[j];
#pragma unroll
    for (int o = 1; o < 64; o <<= 1) { v += __shfl_xor(v, o); wv += __shfl_xor(wv, o); }
    if (lane == 0) {
      const int c = wave + 4 * j;
      atomicAdd(&ssq[b * 384 + h * 24 + c], v);
      atomicAdd(&ssq[b * 384 + 192 + h * 24 + c], wv);
    }
  }
}

// ---------------- fused dwconv(v) + transpose -> VT[b][hw][192] ----------------
// k_vt's proven structure; phase-1 load replaced by on-the-fly dwconv.
__global__ __launch_bounds__(256) void k_dwvt(const unsigned short* __restrict__ QKV,
                                              const float* __restrict__ wd,
                                              unsigned short* __restrict__ VTo) {
  __shared__ unsigned short tile[64 * 72];
  const int pb = blockIdx.x * 64, cb = blockIdx.y * 64, b = blockIdx.z;
  const int t = threadIdx.x;
  const int y = pb >> 7;         // image row of this half-row tile
  const int xs = pb & 127;       // 0 or 64
  {
    const int cl = t >> 2, ps = (t & 3) * 16;
    const int gc = 384 + cb + cl;  // global qkv channel (v part)
    const unsigned short* ip = QKV + ((size_t)b * C3 + gc) * HW;
    const float* w = wd + gc * 9;
    const int x0 = xs + ps;
    float acc[16];
#pragma unroll
    for (int e = 0; e < 16; ++e) acc[e] = 0.f;
#pragma unroll
    for (int dy = 0; dy < 3; ++dy) {
      int yy = y + dy - 1;
      if (yy < 0 || yy > 127) continue;
      const unsigned short* row = ip + yy * 128;
      bfrag v0 = *reinterpret_cast<const bfrag*>(row + x0);
      bfrag v1 = *reinterpret_cast<const bfrag*>(row + x0 + 8);
      float c[16];
#pragma unroll
      for (int e = 0; e < 8; ++e) { c[e] = bf2f_s(v0[e]); c[8 + e] = bf2f_s(v1[e]); }
      float left  = (x0 > 0)   ? bf2f(row[x0 - 1])  : 0.f;
      float right = (x0 < 112) ? bf2f(row[x0 + 16]) : 0.f;
      float wl = w[dy * 3 + 0], wc = w[dy * 3 + 1], wr = w[dy * 3 + 2];
      acc[0] += wl * left + wc * c[0] + wr * c[1];
#pragma unroll
      for (int e = 1; e < 15; ++e) acc[e] += wl * c[e - 1] + wc * c[e] + wr * c[e + 1];
      acc[15] += wl * c[14] + wc * c[15] + wr * right;
    }
    bfrag o0, o1;
#pragma unroll
    for (int e = 0; e < 8; ++e) { o0[e] = (short)f2bf(acc[e]); o1[e] = (short)f2bf(acc[8 + e]); }
    *reinterpret_cast<bfrag*>(&tile[cl * 72 + ps]) = o0;
    *reinterpret_cast<bfrag*>(&tile[cl * 72 + ps + 8]) = o1;
  }
  __syncthreads();
  {
    const int pl = t >> 2, cs = (t & 3) * 16;
    bfrag o0, o1;
#pragma unroll
    for (int e = 0; e < 8; ++e) o0[e] = (short)tile[(cs + e) * 72 + pl];
#pragma unroll
    for (int e = 0; e < 8; ++e) o1[e] = (short)tile[(cs + 8 + e) * 72 + pl];
    unsigned short* dst = VTo + ((size_t)b * HW + pb + pl) * CC + cb + cs;
    *reinterpret_cast<bfrag*>(dst) = o0;
    *reinterpret_cast<bfrag*>(dst + 8) = o1;
  }
}

// ---------------- softmax + M = wproj @ blockdiag(attn), written PACKED ----------------
__global__ __launch_bounds__(64) void k_attn(const float* __restrict__ S,
                                             const float* __restrict__ ssq,
                                             const float* __restrict__ wproj,
                                             const float* __restrict__ temp,
                                             unsigned short* __restrict__ Mp) {
  const int h = blockIdx.x, b = blockIdx.y;
  __shared__ float A[24][25];
  __shared__ float nq[24], nk[24];
  const float* Sb = S + (size_t)(b * 8 + h) * 1024;
  const float* sq = ssq + b * 384 + h * 24;
  const float* sk = ssq + b * 384 + 192 + h * 24;
  const int t = threadIdx.x;
  if (t < 24) {
    nq[t] = fmaxf(sqrtf(sq[t]), 1e-12f);
    nk[t] = fmaxf(sqrtf(sk[t]), 1e-12f);
  }
  __syncthreads();
  if (t < 24) {
    const float tp = temp[h];
    float row[24];
    float mx = -1e30f;
#pragma unroll
    for (int d = 0; d < 24; ++d) {
      row[d] = Sb[t * 32 + d] / (nq[t] * nk[d]) * tp;
      mx = fmaxf(mx, row[d]);
    }
    float s = 0.f;
#pragma unroll
    for (int d = 0; d < 24; ++d) { row[d] = __expf(row[d] - mx); s += row[d]; }
    const float inv = 1.f / s;
#pragma unroll
    for (int d = 0; d < 24; ++d) A[t][d] = row[d] * inv;
  }
  __syncthreads();
  for (int idx = t; idx < 192 * 24; idx += 64) {
    const int o = idx / 24, dd = idx % 24;
    const float* wrow = wproj + o * 192 + h * 24;
    float a = 0.f;
#pragma unroll
    for (int cc = 0; cc < 24; ++cc) a += wrow[cc] * A[cc][dd];
    const int c = h * 24 + dd;
    const int mb = o >> 6, i = (o >> 4) & 3, lr = o & 15;
    const int s = c >> 5, hi = (c >> 3) & 3, e = c & 7;
    const int off = ((mb * 24 + s * 4 + i) * 64 + hi * 16 + lr) * 8 + e;
    Mp[(size_t)b * CC * CC + off] = f2bf(a);
  }
}

// ---------------- out GEMM (R8-proven) ----------------
__global__ __launch_bounds__(256, 3) void k_gemm_out(const unsigned short* __restrict__ Mp,
                                                     const unsigned short* __restrict__ VT,
                                                     float* __restrict__ out) {
  __shared__ __attribute__((aligned(16))) char sB[49152];
  const int nb = blockIdx.x;
  const int b  = blockIdx.y;
  const int tid = threadIdx.x;
  const int wave = tid >> 6, lane = tid & 63;
  const int lrow = lane & 15, lk = (lane >> 4) * 8, lr4 = (lane >> 4) * 4;

  const char* Bc = (const char*)(VT + ((size_t)b * HW + (size_t)nb * 128) * CC);
#pragma unroll
  for (int t = 0; t < 12; ++t) {
    const int L = wave * 12288 + t * 1024 + lane * 16;
    const int row = L / 384;
    const int rem = L - row * 384;
    gl_lds16(Bc + row * 384 + (rem ^ ((row & 7) << 4)), sB + wave * 12288 + t * 1024);
  }
  asm volatile("s_waitcnt vmcnt(0)" ::: "memory");
  __syncthreads();

  const int swz = (lrow & 7) << 4;
  const int base0 = (wave * 32 + lrow) * 384;
  const f32x4 z4 = {0.f, 0.f, 0.f, 0.f};

#pragma unroll 1
  for (int mb = 0; mb < 3; ++mb) {
    const unsigned short* Mb = Mp + (size_t)b * CC * CC + (size_t)mb * 24 * 512;
    bfrag af[6][4];
#pragma unroll
    for (int s = 0; s < 6; ++s)
#pragma unroll
      for (int i = 0; i < 4; ++i)
        af[s][i] = *reinterpret_cast<const bfrag*>(Mb + ((s * 4 + i) * 64 + lane) * 8);

    f32x4 acc[4][2];
#pragma unroll
    for (int i = 0; i < 4; ++i) { acc[i][0] = z4; acc[i][1] = z4; }
#pragma unroll
    for (int s = 0; s < 6; ++s) {
      const int kbs = ((s * 32 + lk) * 2) ^ swz;
      bfrag b0 = *reinterpret_cast<const bfrag*>(sB + base0 + kbs);
      bfrag b1 = *reinterpret_cast<const bfrag*>(sB + base0 + 16 * 384 + kbs);
#pragma unroll
      for (int i = 0; i < 4; ++i) {
        acc[i][0] = MFMA16(b0, af[s][i], acc[i][0]);  // D[px][ch]
        acc[i][1] = MFMA16(b1, af[s][i], acc[i][1]);
      }
    }
    float* Ob = out + ((size_t)b * CC + mb * 64) * HW + nb * 128 + wave * 32;
#pragma unroll
    for (int i = 0; i < 4; ++i) {
      float* rp = Ob + (size_t)(i * 16 + lrow) * HW;
#pragma unroll
      for (int j = 0; j < 2; ++j)
        *reinterpret_cast<f32x4*>(rp + j * 16 + lr4) = acc[i][j];
    }
  }
}

extern "C" void kernel_launch(void* const* d_in, const int* in_sizes, int n_in,
                              void* d_out, int out_size, void* d_ws, size_t ws_size,
                              hipStream_t stream) {
  const float* x      = (const float*)d_in[0];
  const float* w_qkv  = (const float*)d_in[1];
  const float* w_dw   = (const float*)d_in[2];
  const float* w_proj = (const float*)d_in[3];
  const float* temp   = (const float*)d_in[4];
  float* out = (float*)d_out;
  char* ws = (char*)d_ws;

  unsigned short* XT   = (unsigned short*)(ws + OFF_XT);
  unsigned short* VT   = (unsigned short*)(ws + OFF_XT);  // reuse: XT dead after qkv GEMM
  unsigned short* WP   = (unsigned short*)(ws + OFF_WQ);
  unsigned short* QKV  = (unsigned short*)(ws + OFF_QKV);
  float* S   = (float*)(ws + OFF_S);
  float* SSQ = (float*)(ws + OFF_SSQ);
  unsigned short* MP  = (unsigned short*)(ws + OFF_M);

  hipMemsetAsync(ws + OFF_S, 0, SZ_S + SZ_SSQ, stream);
  k_wpack<<<54, 256, 0, stream>>>(w_qkv, WP);
  k_xt<<<dim3(HW / 64, CC / 64, NB), 256, 0, stream>>>(x, XT);
  k_gemm_qkv<<<dim3(HW / 128, NB), 256, 0, stream>>>(WP, XT, QKV);
  k_dwgram<<<dim3(8, NH, NB), 256, 0, stream>>>(QKV, w_dw, S, SSQ);
  k_dwvt<<<dim3(HW / 64, 3, NB), 256, 0, stream>>>(QKV, w_dw, VT);
  k_attn<<<dim3(NH, NB), 64, 0, stream>>>(S, SSQ, w_proj, temp, MP);
  k_gemm_out<<<dim3(HW / 128, NB), 256, 0, stream>>>(MP, VT, out);
}

// Round 10
// 343.909 us; speedup vs baseline: 1.0009x; 1.0009x over previous
//
#include <hip/hip_runtime.h>

#define HW 16384
#define CC 192
#define C3 576
#define NB 8
#define NH 8

typedef __attribute__((ext_vector_type(8))) short bfrag;
typedef __attribute__((ext_vector_type(4))) float f32x4;
typedef __attribute__((ext_vector_type(4))) unsigned short us4;

#define MFMA16(a, b, c) __builtin_amdgcn_mfma_f32_16x16x32_bf16(a, b, c, 0, 0, 0)

typedef __attribute__((address_space(3))) unsigned int lds_u32;
typedef __attribute__((address_space(1))) unsigned int glb_u32;
__device__ __forceinline__ void gl_lds16(const void* g, void* l) {
  __builtin_amdgcn_global_load_lds((const glb_u32*)g, (lds_u32*)l, 16, 0, 0);
}

__device__ __forceinline__ unsigned short f2bf(float f) {
  unsigned int u = __float_as_uint(f);
  u += 0x7fffu + ((u >> 16) & 1u);
  return (unsigned short)(u >> 16);
}
__device__ __forceinline__ float bf2f(unsigned short s) {
  return __uint_as_float(((unsigned int)s) << 16);
}
__device__ __forceinline__ float bf2f_s(short s) {
  return __uint_as_float(((unsigned int)(unsigned short)s) << 16);
}

// ---------------- workspace layout (bytes) ----------------
#define OFF_XT   0ull
#define SZ_XT    ((size_t)NB * HW * CC * 2)      // x transposed bf16 [b][hw][192]; later reused as VT
#define OFF_WQ   (OFF_XT + SZ_XT)
#define SZ_WQ    ((size_t)C3 * CC * 2)           // W packed into MFMA frag order
#define OFF_QKV  (OFF_WQ + SZ_WQ)
#define SZ_QKV   ((size_t)NB * C3 * HW * 2)      // qkv (pre-dw) bf16 [b][576][hw]
#define OFF_S    (OFF_QKV + SZ_QKV)
#define SZ_S     ((size_t)NB * NH * 32 * 32 * 4) // gram fp32 [b][h][32][32]
#define OFF_SSQ  (OFF_S + SZ_S)
#define SZ_SSQ   ((size_t)NB * 384 * 4)          // sumsq fp32 [b][q:192 | k:192]
#define OFF_M    (OFF_SSQ + SZ_SSQ)
#define SZ_M     ((size_t)NB * CC * CC * 2)      // fused proj*attn, packed frag order

// ---------------- prep: x -> bf16 transposed [b][hw][c] ----------------
__global__ __launch_bounds__(256) void k_xt(const float* __restrict__ x,
                                            unsigned short* __restrict__ xt) {
  __shared__ unsigned short tile[64 * 72];
  const int pb = blockIdx.x * 64;
  const int cb = blockIdx.y * 64;
  const int b  = blockIdx.z;
  const int t  = threadIdx.x;
  {
    const int cl = t >> 2, pl = (t & 3) * 16;
    const float* src = x + ((size_t)b * CC + cb + cl) * HW + pb + pl;
    bfrag v0, v1;
#pragma unroll
    for (int q4 = 0; q4 < 2; ++q4) {
      float4 f = *reinterpret_cast<const float4*>(src + q4 * 4);
      v0[q4 * 4 + 0] = (short)f2bf(f.x); v0[q4 * 4 + 1] = (short)f2bf(f.y);
      v0[q4 * 4 + 2] = (short)f2bf(f.z); v0[q4 * 4 + 3] = (short)f2bf(f.w);
    }
#pragma unroll
    for (int q4 = 0; q4 < 2; ++q4) {
      float4 f = *reinterpret_cast<const float4*>(src + 8 + q4 * 4);
      v1[q4 * 4 + 0] = (short)f2bf(f.x); v1[q4 * 4 + 1] = (short)f2bf(f.y);
      v1[q4 * 4 + 2] = (short)f2bf(f.z); v1[q4 * 4 + 3] = (short)f2bf(f.w);
    }
    *reinterpret_cast<bfrag*>(&tile[cl * 72 + pl]) = v0;
    *reinterpret_cast<bfrag*>(&tile[cl * 72 + pl + 8]) = v1;
  }
  __syncthreads();
  {
    const int pl = t >> 2, cl = (t & 3) * 16;
    bfrag o0, o1;
#pragma unroll
    for (int e = 0; e < 8; ++e) o0[e] = (short)tile[(cl + e) * 72 + pl];
#pragma unroll
    for (int e = 0; e < 8; ++e) o1[e] = (short)tile[(cl + 8 + e) * 72 + pl];
    unsigned short* dst = xt + ((size_t)b * HW + pb + pl) * CC + cb + cl;
    *reinterpret_cast<bfrag*>(dst) = o0;
    *reinterpret_cast<bfrag*>(dst + 8) = o1;
  }
}

// ---------------- prep: pack W into MFMA fragment order ----------------
__global__ __launch_bounds__(256) void k_wpack(const float* __restrict__ w,
                                               unsigned short* __restrict__ wp) {
  const int g = blockIdx.x * 256 + threadIdx.x;
  if (g >= 216 * 64) return;
  const int frag = g >> 6, lane = g & 63;
  const int mb = frag / 24, r = frag % 24, s = r >> 2, i = r & 3;
  const int row = mb * 64 + i * 16 + (lane & 15);
  const int col = s * 32 + (lane >> 4) * 8;
  const float* src = w + (size_t)row * CC + col;
  float4 f0 = *reinterpret_cast<const float4*>(src);
  float4 f1 = *reinterpret_cast<const float4*>(src + 4);
  us4 o0, o1;
  o0[0] = f2bf(f0.x); o0[1] = f2bf(f0.y); o0[2] = f2bf(f0.z); o0[3] = f2bf(f0.w);
  o1[0] = f2bf(f1.x); o1[1] = f2bf(f1.y); o1[2] = f2bf(f1.z); o1[3] = f2bf(f1.w);
  *reinterpret_cast<us4*>(wp + (size_t)g * 8) = o0;
  *reinterpret_cast<us4*>(wp + (size_t)g * 8 + 4) = o1;
}

// ---------------- qkv GEMM (R8-proven) ----------------
__global__ __launch_bounds__(256, 3) void k_gemm_qkv(const unsigned short* __restrict__ Wp,
                                                     const unsigned short* __restrict__ Xt,
                                                     unsigned short* __restrict__ Y) {
  __shared__ __attribute__((aligned(16))) char sB[49152];
  const int nb = blockIdx.x;
  const int b  = blockIdx.y;
  const int tid = threadIdx.x;
  const int wave = tid >> 6, lane = tid & 63;
  const int lrow = lane & 15, lk = (lane >> 4) * 8, lr4 = (lane >> 4) * 4;

  const char* Bc = (const char*)(Xt + ((size_t)b * HW + (size_t)nb * 128) * CC);
#pragma unroll
  for (int t = 0; t < 12; ++t) {
    const int L = wave * 12288 + t * 1024 + lane * 16;
    const int row = L / 384;
    const int rem = L - row * 384;
    gl_lds16(Bc + row * 384 + (rem ^ ((row & 7) << 4)), sB + wave * 12288 + t * 1024);
  }
  asm volatile("s_waitcnt vmcnt(0)" ::: "memory");
  __syncthreads();

  const int swz = (lrow & 7) << 4;
  const int base0 = (wave * 32 + lrow) * 384;
  const f32x4 z4 = {0.f, 0.f, 0.f, 0.f};

#pragma unroll 1
  for (int mb = 0; mb < 9; ++mb) {
    const unsigned short* Wb = Wp + (size_t)mb * 24 * 512;
    bfrag af[6][4];
#pragma unroll
    for (int s = 0; s < 6; ++s)
#pragma unroll
      for (int i = 0; i < 4; ++i)
        af[s][i] = *reinterpret_cast<const bfrag*>(Wb + ((s * 4 + i) * 64 + lane) * 8);

    f32x4 acc[4][2];
#pragma unroll
    for (int i = 0; i < 4; ++i) { acc[i][0] = z4; acc[i][1] = z4; }
#pragma unroll
    for (int s = 0; s < 6; ++s) {
      const int kbs = ((s * 32 + lk) * 2) ^ swz;
      bfrag b0 = *reinterpret_cast<const bfrag*>(sB + base0 + kbs);
      bfrag b1 = *reinterpret_cast<const bfrag*>(sB + base0 + 16 * 384 + kbs);
#pragma unroll
      for (int i = 0; i < 4; ++i) {
        acc[i][0] = MFMA16(b0, af[s][i], acc[i][0]);  // D[px][ch]
        acc[i][1] = MFMA16(b1, af[s][i], acc[i][1]);
      }
    }
    unsigned short* Yb = Y + ((size_t)b * C3 + mb * 64) * HW + nb * 128 + wave * 32;
#pragma unroll
    for (int i = 0; i < 4; ++i) {
      unsigned short* rp = Yb + (size_t)(i * 16 + lrow) * HW;
#pragma unroll
      for (int j = 0; j < 2; ++j) {
        uint2 pk;
        pk.x = (unsigned int)f2bf(acc[i][j][0]) | ((unsigned int)f2bf(acc[i][j][1]) << 16);
        pk.y = (unsigned int)f2bf(acc[i][j][2]) | ((unsigned int)f2bf(acc[i][j][3]) << 16);
        *reinterpret_cast<uint2*>(rp + j * 16 + lr4) = pk;
      }
    }
  }
}

// ---------------- fused dwconv(q,k) + gram + ssq ----------------
// R9 structure, but channel loop FULLY UNROLLED so all 12 dwconv8's loads issue
// together (R9's `unroll 1` serialized ~500cy-latency load chains -> 25% VALUBusy).
__global__ __launch_bounds__(256, 2) void k_dwgram(const unsigned short* __restrict__ QKV,
                                                   const float* __restrict__ wd,
                                                   float* __restrict__ S,
                                                   float* __restrict__ ssq) {
  __shared__ short lds[56 * 520];  // rows 0..23 q, 24..47 k, 48..55 slack
  const int strip = blockIdx.x, h = blockIdx.y, b = blockIdx.z;
  const int tid = threadIdx.x, wave = tid >> 6, lane = tid & 63;
  const int lrow = lane & 15, lk8 = (lane >> 4) * 8, lr4 = (lane >> 4) * 4;
  const size_t qbase = ((size_t)b * C3 + h * 24) * HW;
  const size_t kbase = qbase + (size_t)192 * HW;

  const int p = lane * 8;       // px within 512-chunk
  const int x0 = p & 127;

  float sqp[6] = {0.f, 0.f, 0.f, 0.f, 0.f, 0.f};
  float skp[6] = {0.f, 0.f, 0.f, 0.f, 0.f, 0.f};
  f32x4 acc[2][2];
  const f32x4 z4 = {0.f, 0.f, 0.f, 0.f};
#pragma unroll
  for (int i = 0; i < 2; ++i) { acc[i][0] = z4; acc[i][1] = z4; }

  auto dwconv8 = [&](const unsigned short* ip, const float* w, int y, float* facc) {
#pragma unroll
    for (int e = 0; e < 8; ++e) facc[e] = 0.f;
#pragma unroll
    for (int dy = 0; dy < 3; ++dy) {
      int yy = y + dy - 1;
      if (yy < 0 || yy > 127) continue;
      const unsigned short* row = ip + yy * 128;
      bfrag v = *reinterpret_cast<const bfrag*>(row + x0);
      float c[8];
#pragma unroll
      for (int e = 0; e < 8; ++e) c[e] = bf2f_s(v[e]);
      float left  = (x0 > 0)   ? bf2f(row[x0 - 1]) : 0.f;
      float right = (x0 < 120) ? bf2f(row[x0 + 8]) : 0.f;
      float wl = w[dy * 3 + 0], wc = w[dy * 3 + 1], wr = w[dy * 3 + 2];
      facc[0] += wl * left + wc * c[0] + wr * c[1];
#pragma unroll
      for (int e = 1; e < 7; ++e) facc[e] += wl * c[e - 1] + wc * c[e] + wr * c[e + 1];
      facc[7] += wl * c[6] + wc * c[7] + wr * right;
    }
  };

#pragma unroll 1
  for (int chunk = 0; chunk < 4; ++chunk) {
    const int y = strip * 16 + chunk * 4 + (p >> 7);
#pragma unroll
    for (int j = 0; j < 6; ++j) {          // FULL unroll: 12 dwconv load-chains in flight
      const int c = wave + 4 * j;
      float faccq[8], facck[8];
      dwconv8(QKV + qbase + (size_t)c * HW, wd + (h * 24 + c) * 9, y, faccq);
      dwconv8(QKV + kbase + (size_t)c * HW, wd + (192 + h * 24 + c) * 9, y, facck);
      {
        float ss = 0.f;
        bfrag o;
#pragma unroll
        for (int e = 0; e < 8; ++e) { ss += faccq[e] * faccq[e]; o[e] = (short)f2bf(faccq[e]); }
        sqp[j] += ss;
        *reinterpret_cast<bfrag*>(&lds[c * 520 + p]) = o;
      }
      {
        float ss = 0.f;
        bfrag o;
#pragma unroll
        for (int e = 0; e < 8; ++e) { ss += facck[e] * facck[e]; o[e] = (short)f2bf(facck[e]); }
        skp[j] += ss;
        *reinterpret_cast<bfrag*>(&lds[(24 + c) * 520 + p]) = o;
      }
    }
    __syncthreads();
#pragma unroll
    for (int ks = 0; ks < 4; ++ks) {
      const int pp = wave * 128 + ks * 32 + lk8;
      bfrag aq[2], bk[2];
#pragma unroll
      for (int i = 0; i < 2; ++i) {
        aq[i] = *reinterpret_cast<const bfrag*>(&lds[(i * 16 + lrow) * 520 + pp]);
        bk[i] = *reinterpret_cast<const bfrag*>(&lds[(24 + i * 16 + lrow) * 520 + pp]);
      }
#pragma unroll
      for (int i = 0; i < 2; ++i)
#pragma unroll
        for (int j2 = 0; j2 < 2; ++j2) acc[i][j2] = MFMA16(aq[i], bk[j2], acc[i][j2]);
    }
    __syncthreads();
  }

  float* Sb = S + (size_t)(b * 8 + h) * 1024;
#pragma unroll
  for (int i = 0; i < 2; ++i)
#pragma unroll
    for (int j2 = 0; j2 < 2; ++j2)
#pragma unroll
      for (int r = 0; r < 4; ++r)
        atomicAdd(&Sb[(i * 16 + lr4 + r) * 32 + j2 * 16 + lrow], acc[i][j2][r]);

#pragma unroll
  for (int j = 0; j < 6; ++j) {
    float v = sqp[j];
    float wv = skp[j];
#pragma unroll
    for (int o = 1; o < 64; o <<= 1) { v += __shfl_xor(v, o); wv += __shfl_xor(wv, o); }
    if (lane == 0) {
      const int c = wave + 4 * j;
      atomicAdd(&ssq[b * 384 + h * 24 + c], v);
      atomicAdd(&ssq[b * 384 + 192 + h * 24 + c], wv);
    }
  }
}

// ---------------- fused dwconv(v) + transpose -> VT[b][hw][192] ----------------
__global__ __launch_bounds__(256) void k_dwvt(const unsigned short* __restrict__ QKV,
                                              const float* __restrict__ wd,
                                              unsigned short* __restrict__ VTo) {
  __shared__ unsigned short tile[64 * 72];
  const int pb = blockIdx.x * 64, cb = blockIdx.y * 64, b = blockIdx.z;
  const int t = threadIdx.x;
  const int y = pb >> 7;
  const int xs = pb & 127;
  {
    const int cl = t >> 2, ps = (t & 3) * 16;
    const int gc = 384 + cb + cl;
    const unsigned short* ip = QKV + ((size_t)b * C3 + gc) * HW;
    const float* w = wd + gc * 9;
    const int x0 = xs + ps;
    float acc[16];
#pragma unroll
    for (int e = 0; e < 16; ++e) acc[e] = 0.f;
#pragma unroll
    for (int dy = 0; dy < 3; ++dy) {
      int yy = y + dy - 1;
      if (yy < 0 || yy > 127) continue;
      const unsigned short* row = ip + yy * 128;
      bfrag v0 = *reinterpret_cast<const bfrag*>(row + x0);
      bfrag v1 = *reinterpret_cast<const bfrag*>(row + x0 + 8);
      float c[16];
#pragma unroll
      for (int e = 0; e < 8; ++e) { c[e] = bf2f_s(v0[e]); c[8 + e] = bf2f_s(v1[e]); }
      float left  = (x0 > 0)   ? bf2f(row[x0 - 1])  : 0.f;
      float right = (x0 < 112) ? bf2f(row[x0 + 16]) : 0.f;
      float wl = w[dy * 3 + 0], wc = w[dy * 3 + 1], wr = w[dy * 3 + 2];
      acc[0] += wl * left + wc * c[0] + wr * c[1];
#pragma unroll
      for (int e = 1; e < 15; ++e) acc[e] += wl * c[e - 1] + wc * c[e] + wr * c[e + 1];
      acc[15] += wl * c[14] + wc * c[15] + wr * right;
    }
    bfrag o0, o1;
#pragma unroll
    for (int e = 0; e < 8; ++e) { o0[e] = (short)f2bf(acc[e]); o1[e] = (short)f2bf(acc[8 + e]); }
    *reinterpret_cast<bfrag*>(&tile[cl * 72 + ps]) = o0;
    *reinterpret_cast<bfrag*>(&tile[cl * 72 + ps + 8]) = o1;
  }
  __syncthreads();
  {
    const int pl = t >> 2, cs = (t & 3) * 16;
    bfrag o0, o1;
#pragma unroll
    for (int e = 0; e < 8; ++e) o0[e] = (short)tile[(cs + e) * 72 + pl];
#pragma unroll
    for (int e = 0; e < 8; ++e) o1[e] = (short)tile[(cs + 8 + e) * 72 + pl];
    unsigned short* dst = VTo + ((size_t)b * HW + pb + pl) * CC + cb + cs;
    *reinterpret_cast<bfrag*>(dst) = o0;
    *reinterpret_cast<bfrag*>(dst + 8) = o1;
  }
}

// ---------------- softmax + M = wproj @ blockdiag(attn), written PACKED ----------------
__global__ __launch_bounds__(64) void k_attn(const float* __restrict__ S,
                                             const float* __restrict__ ssq,
                                             const float* __restrict__ wproj,
                                             const float* __restrict__ temp,
                                             unsigned short* __restrict__ Mp) {
  const int h = blockIdx.x, b = blockIdx.y;
  __shared__ float A[24][25];
  __shared__ float nq[24], nk[24];
  const float* Sb = S + (size_t)(b * 8 + h) * 1024;
  const float* sq = ssq + b * 384 + h * 24;
  const float* sk = ssq + b * 384 + 192 + h * 24;
  const int t = threadIdx.x;
  if (t < 24) {
    nq[t] = fmaxf(sqrtf(sq[t]), 1e-12f);
    nk[t] = fmaxf(sqrtf(sk[t]), 1e-12f);
  }
  __syncthreads();
  if (t < 24) {
    const float tp = temp[h];
    float row[24];
    float mx = -1e30f;
#pragma unroll
    for (int d = 0; d < 24; ++d) {
      row[d] = Sb[t * 32 + d] / (nq[t] * nk[d]) * tp;
      mx = fmaxf(mx, row[d]);
    }
    float s = 0.f;
#pragma unroll
    for (int d = 0; d < 24; ++d) { row[d] = __expf(row[d] - mx); s += row[d]; }
    const float inv = 1.f / s;
#pragma unroll
    for (int d = 0; d < 24; ++d) A[t][d] = row[d] * inv;
  }
  __syncthreads();
  for (int idx = t; idx < 192 * 24; idx += 64) {
    const int o = idx / 24, dd = idx % 24;
    const float* wrow = wproj + o * 192 + h * 24;
    float a = 0.f;
#pragma unroll
    for (int cc = 0; cc < 24; ++cc) a += wrow[cc] * A[cc][dd];
    const int c = h * 24 + dd;
    const int mb = o >> 6, i = (o >> 4) & 3, lr = o & 15;
    const int s = c >> 5, hi = (c >> 3) & 3, e = c & 7;
    const int off = ((mb * 24 + s * 4 + i) * 64 + hi * 16 + lr) * 8 + e;
    Mp[(size_t)b * CC * CC + off] = f2bf(a);
  }
}

// ---------------- out GEMM (R8-proven) ----------------
__global__ __launch_bounds__(256, 3) void k_gemm_out(const unsigned short* __restrict__ Mp,
                                                     const unsigned short* __restrict__ VT,
                                                     float* __restrict__ out) {
  __shared__ __attribute__((aligned(16))) char sB[49152];
  const int nb = blockIdx.x;
  const int b  = blockIdx.y;
  const int tid = threadIdx.x;
  const int wave = tid >> 6, lane = tid & 63;
  const int lrow = lane & 15, lk = (lane >> 4) * 8, lr4 = (lane >> 4) * 4;

  const char* Bc = (const char*)(VT + ((size_t)b * HW + (size_t)nb * 128) * CC);
#pragma unroll
  for (int t = 0; t < 12; ++t) {
    const int L = wave * 12288 + t * 1024 + lane * 16;
    const int row = L / 384;
    const int rem = L - row * 384;
    gl_lds16(Bc + row * 384 + (rem ^ ((row & 7) << 4)), sB + wave * 12288 + t * 1024);
  }
  asm volatile("s_waitcnt vmcnt(0)" ::: "memory");
  __syncthreads();

  const int swz = (lrow & 7) << 4;
  const int base0 = (wave * 32 + lrow) * 384;
  const f32x4 z4 = {0.f, 0.f, 0.f, 0.f};

#pragma unroll 1
  for (int mb = 0; mb < 3; ++mb) {
    const unsigned short* Mb = Mp + (size_t)b * CC * CC + (size_t)mb * 24 * 512;
    bfrag af[6][4];
#pragma unroll
    for (int s = 0; s < 6; ++s)
#pragma unroll
      for (int i = 0; i < 4; ++i)
        af[s][i] = *reinterpret_cast<const bfrag*>(Mb + ((s * 4 + i) * 64 + lane) * 8);

    f32x4 acc[4][2];
#pragma unroll
    for (int i = 0; i < 4; ++i) { acc[i][0] = z4; acc[i][1] = z4; }
#pragma unroll
    for (int s = 0; s < 6; ++s) {
      const int kbs = ((s * 32 + lk) * 2) ^ swz;
      bfrag b0 = *reinterpret_cast<const bfrag*>(sB + base0 + kbs);
      bfrag b1 = *reinterpret_cast<const bfrag*>(sB + base0 + 16 * 384 + kbs);
#pragma unroll
      for (int i = 0; i < 4; ++i) {
        acc[i][0] = MFMA16(b0, af[s][i], acc[i][0]);  // D[px][ch]
        acc[i][1] = MFMA16(b1, af[s][i], acc[i][1]);
      }
    }
    float* Ob = out + ((size_t)b * CC + mb * 64) * HW + nb * 128 + wave * 32;
#pragma unroll
    for (int i = 0; i < 4; ++i) {
      float* rp = Ob + (size_t)(i * 16 + lrow) * HW;
#pragma unroll
      for (int j = 0; j < 2; ++j)
        *reinterpret_cast<f32x4*>(rp + j * 16 + lr4) = acc[i][j];
    }
  }
}

extern "C" void kernel_launch(void* const* d_in, const int* in_sizes, int n_in,
                              void* d_out, int out_size, void* d_ws, size_t ws_size,
                              hipStream_t stream) {
  const float* x      = (const float*)d_in[0];
  const float* w_qkv  = (const float*)d_in[1];
  const float* w_dw   = (const float*)d_in[2];
  const float* w_proj = (const float*)d_in[3];
  const float* temp   = (const float*)d_in[4];
  float* out = (float*)d_out;
  char* ws = (char*)d_ws;

  unsigned short* XT   = (unsigned short*)(ws + OFF_XT);
  unsigned short* VT   = (unsigned short*)(ws + OFF_XT);  // reuse: XT dead after qkv GEMM
  unsigned short* WP   = (unsigned short*)(ws + OFF_WQ);
  unsigned short* QKV  = (unsigned short*)(ws + OFF_QKV);
  float* S   = (float*)(ws + OFF_S);
  float* SSQ = (float*)(ws + OFF_SSQ);
  unsigned short* MP  = (unsigned short*)(ws + OFF_M);

  hipMemsetAsync(ws + OFF_S, 0, SZ_S + SZ_SSQ, stream);
  k_wpack<<<54, 256, 0, stream>>>(w_qkv, WP);
  k_xt<<<dim3(HW / 64, CC / 64, NB), 256, 0, stream>>>(x, XT);
  k_gemm_qkv<<<dim3(HW / 128, NB), 256, 0, stream>>>(WP, XT, QKV);
  k_dwgram<<<dim3(8, NH, NB), 256, 0, stream>>>(QKV, w_dw, S, SSQ);
  k_dwvt<<<dim3(HW / 64, 3, NB), 256, 0, stream>>>(QKV, w_dw, VT);
  k_attn<<<dim3(NH, NB), 64, 0, stream>>>(S, SSQ, w_proj, temp, MP);
  k_gemm_out<<<dim3(HW / 128, NB), 256, 0, stream>>>(MP, VT, out);
}